// Round 6
// baseline (237.802 us; speedup 1.0000x reference)
//
#include <hip/hip_runtime.h>
#include <hip/hip_bf16.h>
#include <stdint.h>

#define Bsz   16384
#define Tt    79
#define Hh    256
#define Dd    256
#define KP    272    // padded K: 256 h-cols + 3 x rows + 1 bias row + 12 zero pad
#define LROW  280    // LDS row stride in bf16 (560 B)
#define NTILE 32     // batch rows per block
#define THR   128    // 2 waves: wave w = m-HALF, each 128 m-cols x 32 n-rows

typedef __attribute__((ext_vector_type(8)))  short  short8;
typedef __attribute__((ext_vector_type(4)))  float  float4_;
typedef __attribute__((ext_vector_type(16))) float  float16_;

__device__ __forceinline__ unsigned short f2bf(float f){
  unsigned u = __float_as_uint(f);
  u += 0x7fffu + ((u >> 16) & 1u);      // RNE
  return (unsigned short)(u >> 16);
}
// HW packed f32x2 -> bf16x2 (RNE); no builtin on gfx950 (round-5: -11 us).
__device__ __forceinline__ unsigned pk2(float a, float b){
  unsigned r;
  asm("v_cvt_pk_bf16_f32 %0, %1, %2" : "=v"(r) : "v"(a), "v"(b));
  return r;
}

__global__ void build_tables(const float* __restrict__ W_in,
                             const float* __restrict__ U,
                             const float* __restrict__ b_rnn,
                             const float* __restrict__ W_d,
                             const float* __restrict__ b_d,
                             unsigned short* __restrict__ Ut,
                             unsigned short* __restrict__ Wdt){
  const int TBL = 256 * KP;
  int idx = blockIdx.x * 256 + threadIdx.x;
  if (idx >= 2 * TBL) return;
  int tb  = idx / TBL;
  int rem = idx - tb * TBL;
  int m = rem / KP;
  int k = rem - m * KP;
  float v = 0.f;
  if (tb == 0){
    if      (k < 256) v = U[k * 256 + m];
    else if (k < 259) v = W_in[(k - 256) * 256 + m];
    else if (k == 259) v = b_rnn[m];
  } else {
    if      (k < 256) v = W_d[k * 256 + m];
    else if (k == 259) v = b_d[m];
  }
  unsigned short o = f2bf(v);
  if (tb == 0) Ut[rem] = o; else Wdt[rem] = o;
}

// ROUND-6 RESTRUCTURE. Round-5 model: step = MFMA pipe (2196 cyc/SIMD) +
// LDS pipe (~2280 cyc/CU, CU-SHARED) barely overlapping, because all 8
// waves/CU read IDENTICAL B fragments (4-way redundancy per block).
// New shape: 512 blocks x 128 threads (2 waves), 2 blocks/CU, 1 wave/SIMD.
// Each wave owns an m-HALF: 4 MFMA 32x32 tiles x 32 batch rows, afr[4][17]
// (272 regs, AGPR-resident) -- B-read redundancy 4->2, LDS traffic halves
// (~1000 cyc/CU-step << MFMA 2196), AGPR-move VALU per CU halves. MFMA pipe
// becomes the single saturated resource.
__global__ __launch_bounds__(THR, 1) void rnn_main(
    const float* __restrict__ x0,
    const float* __restrict__ x1,
    const float* __restrict__ x2,
    const unsigned short* __restrict__ Ut,
    const unsigned short* __restrict__ Wdt,
    float* __restrict__ out){
  __shared__ __align__(16) short hbuf[2][NTILE * LROW];

  const int tid  = threadIdx.x;
  const int lane = tid & 63;
  const int wm   = tid >> 6;        // m-half 0..1
  const int nrow = lane & 31;       // B operand / C col: batch row
  const int hi   = lane >> 5;       // k-half for A/B fragments
  const int hi8  = hi * 8;
  const int hi4  = hi * 4;
  const int bbase = blockIdx.x * NTILE;

  // ---- zero both LDS buffers (h0 = 0, pad rows = 0) ----
  {
    int4* p = (int4*)&hbuf[0][0];
    const int tot = 2 * NTILE * LROW * 2 / 16;
    int4 z = make_int4(0, 0, 0, 0);
    for (int i = tid; i < tot; i += THR) p[i] = z;
  }
  __syncthreads();

  // bias row (k=259) = 1.0 bf16 in BOTH buffers (never overwritten)
  if (tid < NTILE){
    hbuf[0][tid * LROW + 259] = (short)0x3F80;
    hbuf[1][tid * LROW + 259] = (short)0x3F80;
  }

  // x rows for step t=0 (original time index T-1) into buf 0
  const bool stager = (wm == 0) && (lane < NTILE);
  const int  sn  = lane & (NTILE - 1);
  const int  sgb = bbase + sn;
  if (stager){
    int tr = Tt - 1;
    float a = x0[sgb * Tt + tr];
    float b = x1[sgb * Tt + tr];
    float c = x2[sgb * Tt + tr];
    *(unsigned*)&hbuf[0][sn * LROW + 256] = pk2(a, b);
    hbuf[0][sn * LROW + 258] = (short)f2bf(c);
  }

  // ---- preload A fragments: 4 mt x 17 kt = 68 short8 (272 regs, AGPR) ----
  short8 afr[4][17];
  #pragma unroll
  for (int mt = 0; mt < 4; ++mt){
    const unsigned short* p = Ut + (wm * 128 + mt * 32 + nrow) * KP + hi8;
    #pragma unroll
    for (int kt = 0; kt < 17; ++kt){
      afr[mt][kt] = *(const short8*)(p + kt * 16);
    }
  }

  __syncthreads();

  const float16_ zz = {0.f,0.f,0.f,0.f,0.f,0.f,0.f,0.f,
                       0.f,0.f,0.f,0.f,0.f,0.f,0.f,0.f};
  float16_ acc[4];   // 4 independent chains (one per m-tile)

  // ---- 79 recurrence steps, ONE barrier each (double-buffered h) ----
  #pragma unroll 1
  for (int t = 0; t < Tt; ++t){
    // prefetch x for step t+1 (latency hidden under the K-loop)
    float xa = 0.f, xb = 0.f, xc = 0.f;
    if (stager && t < Tt - 1){
      int tr = Tt - 2 - t;
      xa = x0[sgb * Tt + tr];
      xb = x1[sgb * Tt + tr];
      xc = x2[sgb * Tt + tr];
    }

    const short* hb = &hbuf[t & 1][0];
    short*       hw = &hbuf[(t + 1) & 1][0];
    const short* rbase = &hb[nrow * LROW + hi8];

    __builtin_amdgcn_s_setprio(1);
    #pragma unroll
    for (int kt = 0; kt < 17; ++kt){
      short8 b = *(const short8*)(rbase + kt * 16);
      if (kt == 0){
        #pragma unroll
        for (int mt = 0; mt < 4; ++mt)
          acc[mt] = __builtin_amdgcn_mfma_f32_32x32x16_bf16(afr[mt][0], b, zz, 0, 0, 0);
      } else {
        #pragma unroll
        for (int mt = 0; mt < 4; ++mt)
          acc[mt] = __builtin_amdgcn_mfma_f32_32x32x16_bf16(afr[mt][kt], b, acc[mt], 0, 0, 0);
      }
    }
    __builtin_amdgcn_s_setprio(0);

    // relu + HW pack, write h(t+1) into the OTHER buffer.
    // C/D 32x32 layout: col=lane&31 (=nrow), row m = 8*q + 4*hi + (reg&3)
    #pragma unroll
    for (int mt = 0; mt < 4; ++mt){
      #pragma unroll
      for (int q = 0; q < 4; ++q){
        uint2 w;
        w.x = pk2(fmaxf(acc[mt][4*q+0], 0.f), fmaxf(acc[mt][4*q+1], 0.f));
        w.y = pk2(fmaxf(acc[mt][4*q+2], 0.f), fmaxf(acc[mt][4*q+3], 0.f));
        *(uint2*)&hw[nrow * LROW + wm * 128 + mt * 32 + 8 * q + hi4] = w;
      }
    }
    if (stager && t < Tt - 1){
      *(unsigned*)&hw[sn * LROW + 256] = pk2(xa, xb);
      hw[sn * LROW + 258] = (short)f2bf(xc);
    }

    __syncthreads();   // h(t+1)/x(t+1) visible; next step reads other buffer
  }

  // ---- epilogue: out^T = W_d^T h^T + b_d; final h is in buf[Tt&1] = buf[1] ----
  // (x rows in final buffer are stale but Wdt rows 256-258 are zero; bias row
  //  k=259 is 1.0 and Wdt[.,259] = b_d.)
  const short* hb = &hbuf[Tt & 1][0];
  float16_ oacc[4];
  #pragma unroll
  for (int kt = 0; kt < 17; ++kt){
    short8 b = *(const short8*)&hb[nrow * LROW + kt * 16 + hi8];
    #pragma unroll
    for (int mt = 0; mt < 4; ++mt){
      short8 wf = *(const short8*)(Wdt + (wm * 128 + mt * 32 + nrow) * KP + kt * 16 + hi8);
      if (kt == 0)
        oacc[mt] = __builtin_amdgcn_mfma_f32_32x32x16_bf16(wf, b, zz, 0, 0, 0);
      else
        oacc[mt] = __builtin_amdgcn_mfma_f32_32x32x16_bf16(wf, b, oacc[mt], 0, 0, 0);
    }
  }

  #pragma unroll
  for (int mt = 0; mt < 4; ++mt){
    #pragma unroll
    for (int q = 0; q < 4; ++q){
      float4_ v = {oacc[mt][4*q+0], oacc[mt][4*q+1],
                   oacc[mt][4*q+2], oacc[mt][4*q+3]};
      *(float4_*)&out[(bbase + nrow) * Dd + wm * 128 + mt * 32 + 8 * q + hi4] = v;
    }
  }
}

extern "C" void kernel_launch(void* const* d_in, const int* in_sizes, int n_in,
                              void* d_out, int out_size, void* d_ws, size_t ws_size,
                              hipStream_t stream){
  const float* x0    = (const float*)d_in[0];
  const float* x1    = (const float*)d_in[1];
  const float* x2    = (const float*)d_in[2];
  const float* W_in  = (const float*)d_in[3];
  const float* U     = (const float*)d_in[4];
  const float* b_rnn = (const float*)d_in[5];
  const float* W_d   = (const float*)d_in[6];
  const float* b_d   = (const float*)d_in[7];

  unsigned short* Ut  = (unsigned short*)d_ws;
  unsigned short* Wdt = Ut + 256 * KP;
  float* out = (float*)d_out;

  build_tables<<<(2 * 256 * KP + 255) / 256, 256, 0, stream>>>(W_in, U, b_rnn, W_d, b_d, Ut, Wdt);
  rnn_main<<<Bsz / NTILE, THR, 0, stream>>>(x0, x1, x2, Ut, Wdt, out);
}

// Round 7
// 215.351 us; speedup vs baseline: 1.1043x; 1.1043x over previous
//
#include <hip/hip_runtime.h>
#include <hip/hip_bf16.h>
#include <stdint.h>

#define Bsz   16384
#define Tt    79
#define Hh    256
#define Dd    256
#define KP    272    // padded K: 256 h-cols + 3 x rows + 1 bias row + 12 zero pad
#define LROW  280    // LDS row stride in bf16 (560 B)
#define NTILE 32     // batch rows per block (2 blocks/CU)
#define THR   256    // 4 waves: wave w = m-quarter, each 64 m-cols x 32 n-rows

typedef __attribute__((ext_vector_type(8)))  short  short8;
typedef __attribute__((ext_vector_type(4)))  float  float4_;
typedef __attribute__((ext_vector_type(16))) float  float16_;

__device__ __forceinline__ unsigned short f2bf(float f){
  unsigned u = __float_as_uint(f);
  u += 0x7fffu + ((u >> 16) & 1u);      // RNE
  return (unsigned short)(u >> 16);
}
// HW packed f32x2 -> bf16x2 (RNE); no builtin on gfx950 (round-5: -11 us).
__device__ __forceinline__ unsigned pk2(float a, float b){
  unsigned r;
  asm("v_cvt_pk_bf16_f32 %0, %1, %2" : "=v"(r) : "v"(a), "v"(b));
  return r;
}

__global__ void build_tables(const float* __restrict__ W_in,
                             const float* __restrict__ U,
                             const float* __restrict__ b_rnn,
                             const float* __restrict__ W_d,
                             const float* __restrict__ b_d,
                             unsigned short* __restrict__ Ut,
                             unsigned short* __restrict__ Wdt){
  const int TBL = 256 * KP;
  int idx = blockIdx.x * 256 + threadIdx.x;
  if (idx >= 2 * TBL) return;
  int tb  = idx / TBL;
  int rem = idx - tb * TBL;
  int m = rem / KP;
  int k = rem - m * KP;
  float v = 0.f;
  if (tb == 0){
    if      (k < 256) v = U[k * 256 + m];
    else if (k < 259) v = W_in[(k - 256) * 256 + m];
    else if (k == 259) v = b_rnn[m];
  } else {
    if      (k < 256) v = W_d[k * 256 + m];
    else if (k == 259) v = b_d[m];
  }
  unsigned short o = f2bf(v);
  if (tb == 0) Ut[rem] = o; else Wdt[rem] = o;
}

// 512 blocks x 256 threads = 2 blocks/CU, 2 waves/SIMD (round-6 proved
// 1 wave/SIMD regresses). Model (fits rounds 1-6): per CU-step, MFMA pipe
// 2196 cyc + LDS pipe ~2350 cyc run with ~ZERO overlap because all 8
// waves/CU are phase-aligned (read-burst then MFMA-burst). Round-4's
// blockIdx&1 stagger was a NO-OP: co-resident pairs are (b, b+256) under
// layered dispatch -- same parity. Round-7: placement-robust stagger,
// offset differs by ~1400 cyc for co-resident pairs under EITHER pairing.
__global__ __launch_bounds__(THR, 2) void rnn_main(
    const float* __restrict__ x0,
    const float* __restrict__ x1,
    const float* __restrict__ x2,
    const unsigned short* __restrict__ Ut,
    const unsigned short* __restrict__ Wdt,
    float* __restrict__ out){
  __shared__ __align__(16) short hbuf[2][NTILE * LROW];

  const int tid  = threadIdx.x;
  const int lane = tid & 63;
  const int wm   = tid >> 6;        // m-quarter 0..3
  const int nrow = lane & 31;       // B operand / C col: batch row
  const int hi   = lane >> 5;       // k-half for A/B fragments
  const int hi8  = hi * 8;
  const int hi4  = hi * 4;
  const int bbase = blockIdx.x * NTILE;

  // ---- zero both LDS buffers (h0 = 0, pad rows = 0) ----
  {
    int4* p = (int4*)&hbuf[0][0];
    const int tot = 2 * NTILE * LROW * 2 / 16;
    int4 z = make_int4(0, 0, 0, 0);
    for (int i = tid; i < tot; i += THR) p[i] = z;
  }
  __syncthreads();

  // bias row (k=259) = 1.0 bf16 in BOTH buffers (never overwritten)
  if (tid < NTILE){
    hbuf[0][tid * LROW + 259] = (short)0x3F80;
    hbuf[1][tid * LROW + 259] = (short)0x3F80;
  }

  // x rows for step t=0 (original time index T-1) into buf 0
  const bool stager = (wm == 0) && (lane < NTILE);
  const int  sn  = lane & (NTILE - 1);
  const int  sgb = bbase + sn;
  if (stager){
    int tr = Tt - 1;
    float a = x0[sgb * Tt + tr];
    float b = x1[sgb * Tt + tr];
    float c = x2[sgb * Tt + tr];
    *(unsigned*)&hbuf[0][sn * LROW + 256] = pk2(a, b);
    hbuf[0][sn * LROW + 258] = (short)f2bf(c);
  }

  // ---- preload A fragments: 2 mt x 17 kt = 34 short8 (136 regs) ----
  short8 afr[2][17];
  #pragma unroll
  for (int mt = 0; mt < 2; ++mt){
    const unsigned short* p = Ut + (wm * 64 + mt * 32 + nrow) * KP + hi8;
    #pragma unroll
    for (int kt = 0; kt < 17; ++kt){
      afr[mt][kt] = *(const short8*)(p + kt * 16);
    }
  }

  __syncthreads();

  // ---- anti-phase stagger, placement-robust: co-resident pair is either
  // (2k,2k+1) [bit0 differs] or (b,b+256) [bit8 differs]; in both cases the
  // pair's offsets differ by ~1408 cyc ~ half the anti-phase step.
  {
    int ph = (blockIdx.x & 1) + ((blockIdx.x >> 8) & 1);
    if (ph == 1){
      __builtin_amdgcn_s_sleep(22);                                  // ~1408 cyc
    } else if (ph == 2){
      __builtin_amdgcn_s_sleep(22); __builtin_amdgcn_s_sleep(22);    // ~2816 cyc
    }
  }

  const float16_ zz = {0.f,0.f,0.f,0.f,0.f,0.f,0.f,0.f,
                       0.f,0.f,0.f,0.f,0.f,0.f,0.f,0.f};
  float16_ acc[2];

  // ---- 79 recurrence steps, ONE barrier each (double-buffered h) ----
  #pragma unroll 1
  for (int t = 0; t < Tt; ++t){
    // prefetch x for step t+1 (latency hidden under the K-loop)
    float xa = 0.f, xb = 0.f, xc = 0.f;
    if (stager && t < Tt - 1){
      int tr = Tt - 2 - t;
      xa = x0[sgb * Tt + tr];
      xb = x1[sgb * Tt + tr];
      xc = x2[sgb * Tt + tr];
    }

    const short* hb = &hbuf[t & 1][0];
    short*       hw = &hbuf[(t + 1) & 1][0];
    const short* rbase = &hb[nrow * LROW + hi8];

    __builtin_amdgcn_s_setprio(1);
    #pragma unroll
    for (int kt = 0; kt < 17; ++kt){
      short8 b = *(const short8*)(rbase + kt * 16);
      if (kt == 0){
        acc[0] = __builtin_amdgcn_mfma_f32_32x32x16_bf16(afr[0][0], b, zz, 0, 0, 0);
        acc[1] = __builtin_amdgcn_mfma_f32_32x32x16_bf16(afr[1][0], b, zz, 0, 0, 0);
      } else {
        acc[0] = __builtin_amdgcn_mfma_f32_32x32x16_bf16(afr[0][kt], b, acc[0], 0, 0, 0);
        acc[1] = __builtin_amdgcn_mfma_f32_32x32x16_bf16(afr[1][kt], b, acc[1], 0, 0, 0);
      }
    }
    __builtin_amdgcn_s_setprio(0);

    // relu + HW pack, write h(t+1) into the OTHER buffer.
    // C/D 32x32 layout: col=lane&31 (=nrow), row m = 8*q + 4*hi + (reg&3)
    #pragma unroll
    for (int mt = 0; mt < 2; ++mt){
      #pragma unroll
      for (int q = 0; q < 4; ++q){
        uint2 w;
        w.x = pk2(fmaxf(acc[mt][4*q+0], 0.f), fmaxf(acc[mt][4*q+1], 0.f));
        w.y = pk2(fmaxf(acc[mt][4*q+2], 0.f), fmaxf(acc[mt][4*q+3], 0.f));
        *(uint2*)&hw[nrow * LROW + wm * 64 + mt * 32 + 8 * q + hi4] = w;
      }
    }
    if (stager && t < Tt - 1){
      *(unsigned*)&hw[sn * LROW + 256] = pk2(xa, xb);
      hw[sn * LROW + 258] = (short)f2bf(xc);
    }

    __syncthreads();   // h(t+1)/x(t+1) visible; next step reads other buffer
  }

  // ---- epilogue: out^T = W_d^T h^T + b_d; final h is in buf[Tt&1] = buf[1] ----
  const short* hb = &hbuf[Tt & 1][0];
  float16_ oacc[2];
  #pragma unroll
  for (int kt = 0; kt < 17; ++kt){
    short8 b  = *(const short8*)&hb[nrow * LROW + kt * 16 + hi8];
    short8 w0 = *(const short8*)(Wdt + (wm * 64 +  0 + nrow) * KP + kt * 16 + hi8);
    short8 w1 = *(const short8*)(Wdt + (wm * 64 + 32 + nrow) * KP + kt * 16 + hi8);
    if (kt == 0){
      oacc[0] = __builtin_amdgcn_mfma_f32_32x32x16_bf16(w0, b, zz, 0, 0, 0);
      oacc[1] = __builtin_amdgcn_mfma_f32_32x32x16_bf16(w1, b, zz, 0, 0, 0);
    } else {
      oacc[0] = __builtin_amdgcn_mfma_f32_32x32x16_bf16(w0, b, oacc[0], 0, 0, 0);
      oacc[1] = __builtin_amdgcn_mfma_f32_32x32x16_bf16(w1, b, oacc[1], 0, 0, 0);
    }
  }

  #pragma unroll
  for (int mt = 0; mt < 2; ++mt){
    #pragma unroll
    for (int q = 0; q < 4; ++q){
      float4_ v = {oacc[mt][4*q+0], oacc[mt][4*q+1],
                   oacc[mt][4*q+2], oacc[mt][4*q+3]};
      *(float4_*)&out[(bbase + nrow) * Dd + wm * 64 + mt * 32 + 8 * q + hi4] = v;
    }
  }
}

extern "C" void kernel_launch(void* const* d_in, const int* in_sizes, int n_in,
                              void* d_out, int out_size, void* d_ws, size_t ws_size,
                              hipStream_t stream){
  const float* x0    = (const float*)d_in[0];
  const float* x1    = (const float*)d_in[1];
  const float* x2    = (const float*)d_in[2];
  const float* W_in  = (const float*)d_in[3];
  const float* U     = (const float*)d_in[4];
  const float* b_rnn = (const float*)d_in[5];
  const float* W_d   = (const float*)d_in[6];
  const float* b_d   = (const float*)d_in[7];

  unsigned short* Ut  = (unsigned short*)d_ws;
  unsigned short* Wdt = Ut + 256 * KP;
  float* out = (float*)d_out;

  build_tables<<<(2 * 256 * KP + 255) / 256, 256, 0, stream>>>(W_in, U, b_rnn, W_d, b_d, Ut, Wdt);
  rnn_main<<<Bsz / NTILE, THR, 0, stream>>>(x0, x1, x2, Ut, Wdt, out);
}